// Round 1
// baseline (2903.462 us; speedup 1.0000x reference)
//
#include <hip/hip_runtime.h>

// Problem constants (fixed by the reference file).
#define K_OFF 27
#define M_PTS 100000
#define C_CH 64
#define N_OUT_PTS 400000
#define BN_EPS 1e-5f

// ---------------------------------------------------------------------------
// Kernel 1: gather -> 64x64 matvec -> scatter-add (fp32 atomics)
// Grid: (M/4, K). Block: 256 threads = 4 waves; one wave per point m.
// W[k] staged in LDS (16 KB). x-row broadcast across the wave via __shfl.
// ---------------------------------------------------------------------------
__global__ __launch_bounds__(256) void scatter_gemm(
    const float* __restrict__ x, const float* __restrict__ W,
    const int* __restrict__ in_idx, const int* __restrict__ out_idx,
    float* __restrict__ out_ws)
{
    __shared__ float Wl[C_CH * C_CH];
    const int k = blockIdx.y;
    const float* Wk = W + (size_t)k * C_CH * C_CH;
    for (int i = threadIdx.x; i < C_CH * C_CH; i += 256) Wl[i] = Wk[i];
    __syncthreads();

    const int wave = threadIdx.x >> 6;
    const int lane = threadIdx.x & 63;
    const int m = blockIdx.x * 4 + wave;

    const int base = k * M_PTS + m;          // wave-uniform
    const int src = in_idx[base];            // uniform per wave -> scalarized
    const int dst = out_idx[base];

    const float xv = x[(size_t)src * C_CH + lane];   // coalesced 256B row

    float acc = 0.f;
    #pragma unroll
    for (int i = 0; i < C_CH; ++i) {
        float xi = __shfl(xv, i);
        acc = fmaf(xi, Wl[i * C_CH + lane], acc);    // 2-way bank alias: free
    }

    unsafeAtomicAdd(&out_ws[(size_t)dst * C_CH + lane], acc);
}

// ---------------------------------------------------------------------------
// Kernel 2: per-channel sum and sum-of-squares over the accumulated output.
// Block 256 = 4 waves; each wave reads whole rows (coalesced 256B).
// ---------------------------------------------------------------------------
__global__ __launch_bounds__(256) void bn_stats(
    const float* __restrict__ ws, float* __restrict__ stats)
{
    const int lane = threadIdx.x & 63;   // channel
    const int w = threadIdx.x >> 6;
    float s = 0.f, s2 = 0.f;
    for (int r = blockIdx.x * 4 + w; r < N_OUT_PTS; r += gridDim.x * 4) {
        float v = ws[(size_t)r * C_CH + lane];
        s += v;
        s2 += v * v;
    }
    __shared__ float sh[2][4][C_CH];
    sh[0][w][lane] = s;
    sh[1][w][lane] = s2;
    __syncthreads();
    if (threadIdx.x < C_CH) {
        float ts = sh[0][0][lane] + sh[0][1][lane] + sh[0][2][lane] + sh[0][3][lane];
        float t2 = sh[1][0][lane] + sh[1][1][lane] + sh[1][2][lane] + sh[1][3][lane];
        unsafeAtomicAdd(&stats[lane], ts);
        unsafeAtomicAdd(&stats[C_CH + lane], t2);
    }
}

// ---------------------------------------------------------------------------
// Kernel 3: y = relu((out - mean) * rsqrt(var+eps) * gamma + beta), float4.
// Grid-stride in float4; stride is a multiple of 64 floats so each thread's
// 4 channels are loop-invariant.
// ---------------------------------------------------------------------------
__global__ __launch_bounds__(256) void bn_apply(
    const float* __restrict__ ws, const float* __restrict__ stats,
    const float* __restrict__ gamma, const float* __restrict__ beta,
    float* __restrict__ out)
{
    const float inv_n = 1.0f / (float)N_OUT_PTS;
    const int c0 = (threadIdx.x * 4) & 63;
    float sc[4], bs[4];
    #pragma unroll
    for (int j = 0; j < 4; ++j) {
        int c = c0 + j;
        float mean = stats[c] * inv_n;
        float var = stats[C_CH + c] * inv_n - mean * mean;
        float s = gamma[c] * rsqrtf(var + BN_EPS);
        sc[j] = s;
        bs[j] = beta[c] - mean * s;
    }
    const float4* in4 = (const float4*)ws;
    float4* o4 = (float4*)out;
    const size_t n4 = (size_t)N_OUT_PTS * C_CH / 4;
    const size_t stride = (size_t)gridDim.x * blockDim.x;
    for (size_t i = (size_t)blockIdx.x * blockDim.x + threadIdx.x; i < n4; i += stride) {
        float4 v = in4[i];
        v.x = fmaxf(fmaf(v.x, sc[0], bs[0]), 0.f);
        v.y = fmaxf(fmaf(v.y, sc[1], bs[1]), 0.f);
        v.z = fmaxf(fmaf(v.z, sc[2], bs[2]), 0.f);
        v.w = fmaxf(fmaf(v.w, sc[3], bs[3]), 0.f);
        o4[i] = v;
    }
}

extern "C" void kernel_launch(void* const* d_in, const int* in_sizes, int n_in,
                              void* d_out, int out_size, void* d_ws, size_t ws_size,
                              hipStream_t stream) {
    const float* x      = (const float*)d_in[0];
    const float* W      = (const float*)d_in[1];
    const float* gamma  = (const float*)d_in[2];
    const float* beta   = (const float*)d_in[3];
    const int*   in_idx = (const int*)d_in[4];
    const int*   out_idx= (const int*)d_in[5];
    float* out = (float*)d_out;

    float* out_ws = (float*)d_ws;                         // N_OUT*64 fp32 accumulator
    float* stats  = out_ws + (size_t)N_OUT_PTS * C_CH;    // 128 floats (sum, sumsq)

    const size_t acc_bytes = (size_t)N_OUT_PTS * C_CH * sizeof(float) + 2 * C_CH * sizeof(float);
    hipMemsetAsync(d_ws, 0, acc_bytes, stream);

    dim3 g1(M_PTS / 4, K_OFF);
    scatter_gemm<<<g1, 256, 0, stream>>>(x, W, in_idx, out_idx, out_ws);

    bn_stats<<<2048, 256, 0, stream>>>(out_ws, stats);

    bn_apply<<<2048, 256, 0, stream>>>(out_ws, stats, gamma, beta, out);
}

// Round 2
// 983.177 us; speedup vs baseline: 2.9531x; 2.9531x over previous
//
#include <hip/hip_runtime.h>

// Problem constants (fixed by the reference file).
#define K_OFF 27
#define M_PTS 100000
#define C_CH 64
#define N_OUT_PTS 400000
#define BN_EPS 1e-5f
#define PTS_PER_WAVE 100   // 250 blocks.x * 4 waves * 100 pts = 100000 exactly

// ---------------------------------------------------------------------------
// Kernel 1: gather -> 64x64 matvec -> scatter-add. NO LDS, NO shfl.
// lane = output channel. W[k][:,lane] lives in 64 VGPRs (loaded once per
// wave, amortized over 100 points). The x row address is wave-uniform, so
// x-row reads go through the SCALAR pipe (s_load) -> inner loop is 64 pure
// v_fma_f32 with one SGPR operand. One coalesced 256B row atomic per point.
// ---------------------------------------------------------------------------
__global__ __launch_bounds__(256) void scatter_gemm(
    const float* __restrict__ x, const float* __restrict__ W,
    const int* __restrict__ in_idx, const int* __restrict__ out_idx,
    float* __restrict__ out_ws)
{
    const int k = blockIdx.y;
    const int lane = threadIdx.x & 63;
    // readfirstlane: make wave id provably wave-uniform for the compiler's
    // divergence analysis (tid>>6 alone is treated as divergent).
    const int wave = __builtin_amdgcn_readfirstlane(threadIdx.x >> 6);

    // Stage W[k] column `lane` into registers: w[i] = W[k][i][lane].
    // 64 coalesced dword loads, once per wave.
    const float* __restrict__ Wk = W + (size_t)k * C_CH * C_CH;
    float w[C_CH];
    #pragma unroll
    for (int i = 0; i < C_CH; ++i) w[i] = Wk[i * C_CH + lane];

    const int m0 = (blockIdx.x * 4 + wave) * PTS_PER_WAVE;
    const int base = k * M_PTS + m0;   // wave-uniform

    for (int p = 0; p < PTS_PER_WAVE; ++p) {
        // Uniform addresses -> scalar loads.
        int src = __builtin_amdgcn_readfirstlane(in_idx[base + p]);
        int dst = __builtin_amdgcn_readfirstlane(out_idx[base + p]);

        const float4* __restrict__ xr = (const float4*)(x + (size_t)src * C_CH);
        // Two independent accumulators to break the fma dependency chain.
        float a0 = 0.f, a1 = 0.f;
        #pragma unroll
        for (int j = 0; j < 16; j += 2) {
            float4 u = xr[j];       // wave-uniform -> s_load_dwordx4
            float4 v = xr[j + 1];
            a0 = fmaf(u.x, w[4 * j + 0], a0);
            a0 = fmaf(u.y, w[4 * j + 1], a0);
            a0 = fmaf(u.z, w[4 * j + 2], a0);
            a0 = fmaf(u.w, w[4 * j + 3], a0);
            a1 = fmaf(v.x, w[4 * j + 4], a1);
            a1 = fmaf(v.y, w[4 * j + 5], a1);
            a1 = fmaf(v.z, w[4 * j + 6], a1);
            a1 = fmaf(v.w, w[4 * j + 7], a1);
        }
        unsafeAtomicAdd(&out_ws[(size_t)dst * C_CH + lane], a0 + a1);
    }
}

// ---------------------------------------------------------------------------
// Kernel 2: per-channel sum and sum-of-squares over the accumulated output.
// ---------------------------------------------------------------------------
__global__ __launch_bounds__(256) void bn_stats(
    const float* __restrict__ ws, float* __restrict__ stats)
{
    const int lane = threadIdx.x & 63;   // channel
    const int w = threadIdx.x >> 6;
    float s = 0.f, s2 = 0.f;
    for (int r = blockIdx.x * 4 + w; r < N_OUT_PTS; r += gridDim.x * 4) {
        float v = ws[(size_t)r * C_CH + lane];
        s += v;
        s2 += v * v;
    }
    __shared__ float sh[2][4][C_CH];
    sh[0][w][lane] = s;
    sh[1][w][lane] = s2;
    __syncthreads();
    if (threadIdx.x < C_CH) {
        float ts = sh[0][0][lane] + sh[0][1][lane] + sh[0][2][lane] + sh[0][3][lane];
        float t2 = sh[1][0][lane] + sh[1][1][lane] + sh[1][2][lane] + sh[1][3][lane];
        unsafeAtomicAdd(&stats[lane], ts);
        unsafeAtomicAdd(&stats[C_CH + lane], t2);
    }
}

// ---------------------------------------------------------------------------
// Kernel 3: y = relu((out - mean) * rsqrt(var+eps) * gamma + beta), float4.
// ---------------------------------------------------------------------------
__global__ __launch_bounds__(256) void bn_apply(
    const float* __restrict__ ws, const float* __restrict__ stats,
    const float* __restrict__ gamma, const float* __restrict__ beta,
    float* __restrict__ out)
{
    const float inv_n = 1.0f / (float)N_OUT_PTS;
    const int c0 = (threadIdx.x * 4) & 63;
    float sc[4], bs[4];
    #pragma unroll
    for (int j = 0; j < 4; ++j) {
        int c = c0 + j;
        float mean = stats[c] * inv_n;
        float var = stats[C_CH + c] * inv_n - mean * mean;
        float s = gamma[c] * rsqrtf(var + BN_EPS);
        sc[j] = s;
        bs[j] = beta[c] - mean * s;
    }
    const float4* in4 = (const float4*)ws;
    float4* o4 = (float4*)out;
    const size_t n4 = (size_t)N_OUT_PTS * C_CH / 4;
    const size_t stride = (size_t)gridDim.x * blockDim.x;
    for (size_t i = (size_t)blockIdx.x * blockDim.x + threadIdx.x; i < n4; i += stride) {
        float4 v = in4[i];
        v.x = fmaxf(fmaf(v.x, sc[0], bs[0]), 0.f);
        v.y = fmaxf(fmaf(v.y, sc[1], bs[1]), 0.f);
        v.z = fmaxf(fmaf(v.z, sc[2], bs[2]), 0.f);
        v.w = fmaxf(fmaf(v.w, sc[3], bs[3]), 0.f);
        o4[i] = v;
    }
}

extern "C" void kernel_launch(void* const* d_in, const int* in_sizes, int n_in,
                              void* d_out, int out_size, void* d_ws, size_t ws_size,
                              hipStream_t stream) {
    const float* x      = (const float*)d_in[0];
    const float* W      = (const float*)d_in[1];
    const float* gamma  = (const float*)d_in[2];
    const float* beta   = (const float*)d_in[3];
    const int*   in_idx = (const int*)d_in[4];
    const int*   out_idx= (const int*)d_in[5];
    float* out = (float*)d_out;

    float* out_ws = (float*)d_ws;                         // N_OUT*64 fp32 accumulator
    float* stats  = out_ws + (size_t)N_OUT_PTS * C_CH;    // 128 floats (sum, sumsq)

    const size_t acc_bytes = (size_t)N_OUT_PTS * C_CH * sizeof(float) + 2 * C_CH * sizeof(float);
    hipMemsetAsync(d_ws, 0, acc_bytes, stream);

    dim3 g1(M_PTS / (4 * PTS_PER_WAVE), K_OFF);   // (250, 27)
    scatter_gemm<<<g1, 256, 0, stream>>>(x, W, in_idx, out_idx, out_ws);

    bn_stats<<<2048, 256, 0, stream>>>(out_ws, stats);

    bn_apply<<<2048, 256, 0, stream>>>(out_ws, stats, gamma, beta, out);
}

// Round 4
// 839.849 us; speedup vs baseline: 3.4571x; 1.1707x over previous
//
#include <hip/hip_runtime.h>

// Problem constants (fixed by the reference file).
#define K_OFF 27
#define M_PTS 100000
#define C_CH 64
#define N_OUT_PTS 400000
#define BN_EPS 1e-5f
#define PTS_PER_WAVE 50   // 500 blocks.x * 4 waves * 50 pts = 100000 exactly

// ---------------------------------------------------------------------------
// Kernel 1: gather -> 64x64 matvec -> scatter-add.
// lane = output channel. W[k][:,lane] in VGPRs. Indices for all 50 points
// loaded lane-parallel once, broadcast per point with v_readlane (keeps the
// x-row address wave-uniform -> scalar-pipe s_load_dwordx4, free broadcast
// into v_fma's SGPR operand). x rows ping-pong through u/v (FULL 16-float4
// rows — round 3's bug was 8) so row p+2's loads fly during p/p+1's FMAs.
// launch_bounds(256,2): SGPR file (~102) can't hold two rows + w; give the
// compiler a 256-VGPR budget to stream one buffer through VGPRs.
// ---------------------------------------------------------------------------
__global__ __launch_bounds__(256, 2) void scatter_gemm(
    const float* __restrict__ x, const float* __restrict__ W,
    const int* __restrict__ in_idx, const int* __restrict__ out_idx,
    float* __restrict__ out_ws)
{
    const int k = blockIdx.y;
    const int lane = threadIdx.x & 63;
    const int wave = __builtin_amdgcn_readfirstlane(threadIdx.x >> 6);

    // W[k] column `lane` into registers (amortized over 50 points).
    const float* __restrict__ Wk = W + (size_t)k * C_CH * C_CH;
    float w[C_CH];
    #pragma unroll
    for (int i = 0; i < C_CH; ++i) w[i] = Wk[i * C_CH + lane];

    const int m0 = (blockIdx.x * 4 + wave) * PTS_PER_WAVE;
    const int base = k * M_PTS + m0;   // wave-uniform

    // Lane-parallel index load: lane p holds point p's indices (p < 50).
    const int li = lane < PTS_PER_WAVE ? lane : PTS_PER_WAVE - 1;
    const int vsrc = in_idx[base + li];
    const int vdst = out_idx[base + li];

    // Preload FULL rows (16 float4 = 64 floats) for points 0 and 1.
    float4 u[16], v[16];
    {
        int s0 = __builtin_amdgcn_readlane(vsrc, 0);
        const float4* xr = (const float4*)(x + (size_t)s0 * C_CH);
        #pragma unroll
        for (int j = 0; j < 16; ++j) u[j] = xr[j];
        int s1 = __builtin_amdgcn_readlane(vsrc, 1);
        const float4* xs = (const float4*)(x + (size_t)s1 * C_CH);
        #pragma unroll
        for (int j = 0; j < 16; ++j) v[j] = xs[j];
    }

    for (int p = 0; p < PTS_PER_WAVE; p += 2) {
        // ---- point p (buffer u) ----
        {
            float a0 = 0.f, a1 = 0.f;
            #pragma unroll
            for (int j = 0; j < 16; j += 2) {
                float4 t0 = u[j], t1 = u[j + 1];
                a0 = fmaf(t0.x, w[4 * j + 0], a0);
                a0 = fmaf(t0.y, w[4 * j + 1], a0);
                a0 = fmaf(t0.z, w[4 * j + 2], a0);
                a0 = fmaf(t0.w, w[4 * j + 3], a0);
                a1 = fmaf(t1.x, w[4 * j + 4], a1);
                a1 = fmaf(t1.y, w[4 * j + 5], a1);
                a1 = fmaf(t1.z, w[4 * j + 6], a1);
                a1 = fmaf(t1.w, w[4 * j + 7], a1);
            }
            int dst = __builtin_amdgcn_readlane(vdst, p);
            unsafeAtomicAdd(&out_ws[(size_t)dst * C_CH + lane], a0 + a1);
        }
        // refill u with row p+2 (hides behind point p+1's compute)
        {
            int pn = (p + 2 < PTS_PER_WAVE) ? p + 2 : PTS_PER_WAVE - 1;
            int sn = __builtin_amdgcn_readlane(vsrc, pn);
            const float4* xr = (const float4*)(x + (size_t)sn * C_CH);
            #pragma unroll
            for (int j = 0; j < 16; ++j) u[j] = xr[j];
        }
        // ---- point p+1 (buffer v) ----
        {
            float a0 = 0.f, a1 = 0.f;
            #pragma unroll
            for (int j = 0; j < 16; j += 2) {
                float4 t0 = v[j], t1 = v[j + 1];
                a0 = fmaf(t0.x, w[4 * j + 0], a0);
                a0 = fmaf(t0.y, w[4 * j + 1], a0);
                a0 = fmaf(t0.z, w[4 * j + 2], a0);
                a0 = fmaf(t0.w, w[4 * j + 3], a0);
                a1 = fmaf(t1.x, w[4 * j + 4], a1);
                a1 = fmaf(t1.y, w[4 * j + 5], a1);
                a1 = fmaf(t1.z, w[4 * j + 6], a1);
                a1 = fmaf(t1.w, w[4 * j + 7], a1);
            }
            int dst = __builtin_amdgcn_readlane(vdst, p + 1);
            unsafeAtomicAdd(&out_ws[(size_t)dst * C_CH + lane], a0 + a1);
        }
        // refill v with row p+3
        {
            int pn = (p + 3 < PTS_PER_WAVE) ? p + 3 : PTS_PER_WAVE - 1;
            int sn = __builtin_amdgcn_readlane(vsrc, pn);
            const float4* xs = (const float4*)(x + (size_t)sn * C_CH);
            #pragma unroll
            for (int j = 0; j < 16; ++j) v[j] = xs[j];
        }
    }
}

// ---------------------------------------------------------------------------
// Kernel 2: per-channel sum / sum-of-squares, float4 grid-stride.
// Stride is a multiple of 64 floats so each thread's 4 channels are fixed.
// ---------------------------------------------------------------------------
__global__ __launch_bounds__(256) void bn_stats(
    const float* __restrict__ ws, float* __restrict__ stats)
{
    const float4* in4 = (const float4*)ws;
    const size_t n4 = (size_t)N_OUT_PTS * C_CH / 4;
    const size_t stride = (size_t)gridDim.x * blockDim.x;
    float s[4] = {0, 0, 0, 0}, s2[4] = {0, 0, 0, 0};
    for (size_t i = (size_t)blockIdx.x * blockDim.x + threadIdx.x; i < n4; i += stride) {
        float4 t = in4[i];
        s[0] += t.x; s2[0] += t.x * t.x;
        s[1] += t.y; s2[1] += t.y * t.y;
        s[2] += t.z; s2[2] += t.z * t.z;
        s[3] += t.w; s2[3] += t.w * t.w;
    }
    // Thread t covers channels 4*(t&15)+j.  Reduce in LDS.
    __shared__ float sh[2][256][4];
    #pragma unroll
    for (int j = 0; j < 4; ++j) { sh[0][threadIdx.x][j] = s[j]; sh[1][threadIdx.x][j] = s2[j]; }
    __syncthreads();
    if (threadIdx.x < C_CH) {
        const int c = threadIdx.x;
        float ts = 0.f, t2 = 0.f;
        #pragma unroll
        for (int j = 0; j < 16; ++j) {      // threads with same channel set
            ts += sh[0][(c >> 2) + 16 * j][c & 3];
            t2 += sh[1][(c >> 2) + 16 * j][c & 3];
        }
        unsafeAtomicAdd(&stats[c], ts);
        unsafeAtomicAdd(&stats[C_CH + c], t2);
    }
}

// ---------------------------------------------------------------------------
// Kernel 3: y = relu((out - mean) * rsqrt(var+eps) * gamma + beta), float4.
// ---------------------------------------------------------------------------
__global__ __launch_bounds__(256) void bn_apply(
    const float* __restrict__ ws, const float* __restrict__ stats,
    const float* __restrict__ gamma, const float* __restrict__ beta,
    float* __restrict__ out)
{
    const float inv_n = 1.0f / (float)N_OUT_PTS;
    const int c0 = (threadIdx.x * 4) & 63;
    float sc[4], bs[4];
    #pragma unroll
    for (int j = 0; j < 4; ++j) {
        int c = c0 + j;
        float mean = stats[c] * inv_n;
        float var = stats[C_CH + c] * inv_n - mean * mean;
        float s = gamma[c] * rsqrtf(var + BN_EPS);
        sc[j] = s;
        bs[j] = beta[c] - mean * s;
    }
    const float4* in4 = (const float4*)ws;
    float4* o4 = (float4*)out;
    const size_t n4 = (size_t)N_OUT_PTS * C_CH / 4;
    const size_t stride = (size_t)gridDim.x * blockDim.x;
    for (size_t i = (size_t)blockIdx.x * blockDim.x + threadIdx.x; i < n4; i += stride) {
        float4 v = in4[i];
        v.x = fmaxf(fmaf(v.x, sc[0], bs[0]), 0.f);
        v.y = fmaxf(fmaf(v.y, sc[1], bs[1]), 0.f);
        v.z = fmaxf(fmaf(v.z, sc[2], bs[2]), 0.f);
        v.w = fmaxf(fmaf(v.w, sc[3], bs[3]), 0.f);
        o4[i] = v;
    }
}

extern "C" void kernel_launch(void* const* d_in, const int* in_sizes, int n_in,
                              void* d_out, int out_size, void* d_ws, size_t ws_size,
                              hipStream_t stream) {
    const float* x      = (const float*)d_in[0];
    const float* W      = (const float*)d_in[1];
    const float* gamma  = (const float*)d_in[2];
    const float* beta   = (const float*)d_in[3];
    const int*   in_idx = (const int*)d_in[4];
    const int*   out_idx= (const int*)d_in[5];
    float* out = (float*)d_out;

    float* out_ws = (float*)d_ws;                         // N_OUT*64 fp32 accumulator
    float* stats  = out_ws + (size_t)N_OUT_PTS * C_CH;    // 128 floats (sum, sumsq)

    const size_t acc_bytes = (size_t)N_OUT_PTS * C_CH * sizeof(float) + 2 * C_CH * sizeof(float);
    hipMemsetAsync(d_ws, 0, acc_bytes, stream);

    dim3 g1(M_PTS / (4 * PTS_PER_WAVE), K_OFF);   // (500, 27)
    scatter_gemm<<<g1, 256, 0, stream>>>(x, W, in_idx, out_idx, out_ws);

    bn_stats<<<2048, 256, 0, stream>>>(out_ws, stats);

    bn_apply<<<2048, 256, 0, stream>>>(out_ws, stats, gamma, beta, out);
}

// Round 6
// 706.492 us; speedup vs baseline: 4.1097x; 1.1888x over previous
//
#include <hip/hip_runtime.h>
#include <hip/hip_bf16.h>

// Problem constants (fixed by the reference file).
#define K_OFF 27
#define M_PTS 100000
#define C_CH 64
#define N_OUT_PTS 400000
#define BN_EPS 1e-5f
#define PTS_PER_WAVE 50   // 500 blocks.x * 4 waves * 50 pts = 100000 exactly

// Packed 2xbf16 atomic add. gfx950 HAS global_atomic_pk_add_bf16 (CDNA3+);
// packed-fp32 atomics do NOT exist (round-5 compile fail).
__device__ inline void pk_atomic_add_bf16(__hip_bfloat16* p, int bits) {
#if __has_builtin(__builtin_amdgcn_global_atomic_fadd_v2bf16)
    typedef short s2v __attribute__((ext_vector_type(2)));
    typedef __attribute__((address_space(1))) s2v* gp;
    s2v v;
    __builtin_memcpy(&v, &bits, 4);
    __builtin_amdgcn_global_atomic_fadd_v2bf16((gp)(unsigned long long)p, v);
#else
    asm volatile("global_atomic_pk_add_bf16 %0, %1, off"
                 :: "v"((unsigned long long)p), "v"(bits) : "memory");
#endif
}

// ---------------------------------------------------------------------------
// Kernel 1: gather -> 64x64 matvec -> scatter-add (packed bf16 atomics).
// Round-4 proven core: lane = channel, W[k] column in regs, lane-parallel
// index load + readlane broadcast (scalar-pipe x-row loads), u/v full-row
// double buffer. New tail: channels pair up via 2 shfl; lanes 0-31 issue one
// global_atomic_pk_add_bf16 (1 dword = 2 channels) -> 32 atomic dwords/point
// instead of 64. Accumulator is bf16 (precision budget checked vs 0.1375).
// ---------------------------------------------------------------------------
__global__ __launch_bounds__(256, 2) void scatter_gemm(
    const float* __restrict__ x, const float* __restrict__ W,
    const int* __restrict__ in_idx, const int* __restrict__ out_idx,
    __hip_bfloat16* __restrict__ out_ws)
{
    const int k = blockIdx.y;
    const int lane = threadIdx.x & 63;
    const int wave = __builtin_amdgcn_readfirstlane(threadIdx.x >> 6);

    const float* __restrict__ Wk = W + (size_t)k * C_CH * C_CH;
    float w[C_CH];
    #pragma unroll
    for (int i = 0; i < C_CH; ++i) w[i] = Wk[i * C_CH + lane];

    const int m0 = (blockIdx.x * 4 + wave) * PTS_PER_WAVE;
    const int base = k * M_PTS + m0;   // wave-uniform

    const int li = lane < PTS_PER_WAVE ? lane : PTS_PER_WAVE - 1;
    const int vsrc = in_idx[base + li];
    const int vdst = out_idx[base + li];

    float4 u[16], v[16];
    {
        int s0 = __builtin_amdgcn_readlane(vsrc, 0);
        const float4* xr = (const float4*)(x + (size_t)s0 * C_CH);
        #pragma unroll
        for (int j = 0; j < 16; ++j) u[j] = xr[j];
        int s1 = __builtin_amdgcn_readlane(vsrc, 1);
        const float4* xs = (const float4*)(x + (size_t)s1 * C_CH);
        #pragma unroll
        for (int j = 0; j < 16; ++j) v[j] = xs[j];
    }

    const int pl = lane & 31;   // pair id for the atomic tail

    for (int p = 0; p < PTS_PER_WAVE; p += 2) {
        // ---- point p (buffer u) ----
        {
            float a0 = 0.f, a1 = 0.f;
            #pragma unroll
            for (int j = 0; j < 16; j += 2) {
                float4 t0 = u[j], t1 = u[j + 1];
                a0 = fmaf(t0.x, w[4 * j + 0], a0);
                a0 = fmaf(t0.y, w[4 * j + 1], a0);
                a0 = fmaf(t0.z, w[4 * j + 2], a0);
                a0 = fmaf(t0.w, w[4 * j + 3], a0);
                a1 = fmaf(t1.x, w[4 * j + 4], a1);
                a1 = fmaf(t1.y, w[4 * j + 5], a1);
                a1 = fmaf(t1.z, w[4 * j + 6], a1);
                a1 = fmaf(t1.w, w[4 * j + 7], a1);
            }
            float val = a0 + a1;
            int dst = __builtin_amdgcn_readlane(vdst, p);
            float lo = __shfl(val, 2 * pl);
            float hi = __shfl(val, 2 * pl + 1);
            if (lane < 32) {
                union { __hip_bfloat162 h; int i; } cv;
                cv.h = __hip_bfloat162(__float2bfloat16(lo), __float2bfloat16(hi));
                pk_atomic_add_bf16(out_ws + (size_t)dst * C_CH + 2 * lane, cv.i);
            }
        }
        // refill u with row p+2 (hides behind point p+1's compute)
        {
            int pn = (p + 2 < PTS_PER_WAVE) ? p + 2 : PTS_PER_WAVE - 1;
            int sn = __builtin_amdgcn_readlane(vsrc, pn);
            const float4* xr = (const float4*)(x + (size_t)sn * C_CH);
            #pragma unroll
            for (int j = 0; j < 16; ++j) u[j] = xr[j];
        }
        // ---- point p+1 (buffer v) ----
        {
            float a0 = 0.f, a1 = 0.f;
            #pragma unroll
            for (int j = 0; j < 16; j += 2) {
                float4 t0 = v[j], t1 = v[j + 1];
                a0 = fmaf(t0.x, w[4 * j + 0], a0);
                a0 = fmaf(t0.y, w[4 * j + 1], a0);
                a0 = fmaf(t0.z, w[4 * j + 2], a0);
                a0 = fmaf(t0.w, w[4 * j + 3], a0);
                a1 = fmaf(t1.x, w[4 * j + 4], a1);
                a1 = fmaf(t1.y, w[4 * j + 5], a1);
                a1 = fmaf(t1.z, w[4 * j + 6], a1);
                a1 = fmaf(t1.w, w[4 * j + 7], a1);
            }
            float val = a0 + a1;
            int dst = __builtin_amdgcn_readlane(vdst, p + 1);
            float lo = __shfl(val, 2 * pl);
            float hi = __shfl(val, 2 * pl + 1);
            if (lane < 32) {
                union { __hip_bfloat162 h; int i; } cv;
                cv.h = __hip_bfloat162(__float2bfloat16(lo), __float2bfloat16(hi));
                pk_atomic_add_bf16(out_ws + (size_t)dst * C_CH + 2 * lane, cv.i);
            }
        }
        // refill v with row p+3
        {
            int pn = (p + 3 < PTS_PER_WAVE) ? p + 3 : PTS_PER_WAVE - 1;
            int sn = __builtin_amdgcn_readlane(vsrc, pn);
            const float4* xs = (const float4*)(x + (size_t)sn * C_CH);
            #pragma unroll
            for (int j = 0; j < 16; ++j) v[j] = xs[j];
        }
    }
}

// ---------------------------------------------------------------------------
// Kernel 2: per-channel sum / sumsq over bf16 accumulator. uint4 = 8 bf16
// per load; stride multiple of 64 ch so each thread owns 8 fixed channels.
// ---------------------------------------------------------------------------
__global__ __launch_bounds__(256) void bn_stats(
    const __hip_bfloat16* __restrict__ ws, float* __restrict__ stats)
{
    const uint4* in = (const uint4*)ws;
    const size_t n = (size_t)N_OUT_PTS * C_CH / 8;   // 3.2M uint4s
    const size_t stride = (size_t)gridDim.x * blockDim.x;
    float s[8], s2[8];
    #pragma unroll
    for (int j = 0; j < 8; ++j) { s[j] = 0.f; s2[j] = 0.f; }
    for (size_t i = (size_t)blockIdx.x * blockDim.x + threadIdx.x; i < n; i += stride) {
        uint4 q = in[i];
        unsigned wds[4] = {q.x, q.y, q.z, q.w};
        #pragma unroll
        for (int j = 0; j < 4; ++j) {
            __hip_bfloat162 h = *(__hip_bfloat162*)&wds[j];
            float f0 = __low2float(h), f1 = __high2float(h);
            s[2 * j] += f0;  s2[2 * j] += f0 * f0;
            s[2 * j + 1] += f1; s2[2 * j + 1] += f1 * f1;
        }
    }
    // thread t owns channels 8*(t&7)+j
    __shared__ float sh[2][256][8];
    #pragma unroll
    for (int j = 0; j < 8; ++j) { sh[0][threadIdx.x][j] = s[j]; sh[1][threadIdx.x][j] = s2[j]; }
    __syncthreads();
    if (threadIdx.x < C_CH) {
        const int c = threadIdx.x;
        float ts = 0.f, t2 = 0.f;
        #pragma unroll
        for (int q = 0; q < 32; ++q) {
            ts += sh[0][8 * q + (c >> 3)][c & 7];
            t2 += sh[1][8 * q + (c >> 3)][c & 7];
        }
        unsafeAtomicAdd(&stats[c], ts);
        unsafeAtomicAdd(&stats[C_CH + c], t2);
    }
}

// ---------------------------------------------------------------------------
// Kernel 3: y = relu((ws - mean) * rsqrt(var+eps) * gamma + beta).
// Reads bf16 accumulator (uint4 = 8 ch), writes fp32 out (2x float4).
// ---------------------------------------------------------------------------
__global__ __launch_bounds__(256) void bn_apply(
    const __hip_bfloat16* __restrict__ ws, const float* __restrict__ stats,
    const float* __restrict__ gamma, const float* __restrict__ beta,
    float* __restrict__ out)
{
    const float inv_n = 1.0f / (float)N_OUT_PTS;
    const int c0 = 8 * (threadIdx.x & 7);
    float sc[8], bs[8];
    #pragma unroll
    for (int j = 0; j < 8; ++j) {
        int c = c0 + j;
        float mean = stats[c] * inv_n;
        float var = stats[C_CH + c] * inv_n - mean * mean;
        float s = gamma[c] * rsqrtf(var + BN_EPS);
        sc[j] = s;
        bs[j] = beta[c] - mean * s;
    }
    const uint4* in = (const uint4*)ws;
    float4* o4 = (float4*)out;
    const size_t n = (size_t)N_OUT_PTS * C_CH / 8;
    const size_t stride = (size_t)gridDim.x * blockDim.x;
    for (size_t i = (size_t)blockIdx.x * blockDim.x + threadIdx.x; i < n; i += stride) {
        uint4 q = in[i];
        unsigned wds[4] = {q.x, q.y, q.z, q.w};
        float f[8];
        #pragma unroll
        for (int j = 0; j < 4; ++j) {
            __hip_bfloat162 h = *(__hip_bfloat162*)&wds[j];
            f[2 * j] = __low2float(h);
            f[2 * j + 1] = __high2float(h);
        }
        float4 r0, r1;
        r0.x = fmaxf(fmaf(f[0], sc[0], bs[0]), 0.f);
        r0.y = fmaxf(fmaf(f[1], sc[1], bs[1]), 0.f);
        r0.z = fmaxf(fmaf(f[2], sc[2], bs[2]), 0.f);
        r0.w = fmaxf(fmaf(f[3], sc[3], bs[3]), 0.f);
        r1.x = fmaxf(fmaf(f[4], sc[4], bs[4]), 0.f);
        r1.y = fmaxf(fmaf(f[5], sc[5], bs[5]), 0.f);
        r1.z = fmaxf(fmaf(f[6], sc[6], bs[6]), 0.f);
        r1.w = fmaxf(fmaf(f[7], sc[7], bs[7]), 0.f);
        o4[2 * i] = r0;
        o4[2 * i + 1] = r1;
    }
}

extern "C" void kernel_launch(void* const* d_in, const int* in_sizes, int n_in,
                              void* d_out, int out_size, void* d_ws, size_t ws_size,
                              hipStream_t stream) {
    const float* x      = (const float*)d_in[0];
    const float* W      = (const float*)d_in[1];
    const float* gamma  = (const float*)d_in[2];
    const float* beta   = (const float*)d_in[3];
    const int*   in_idx = (const int*)d_in[4];
    const int*   out_idx= (const int*)d_in[5];
    float* out = (float*)d_out;

    __hip_bfloat16* out_ws = (__hip_bfloat16*)d_ws;       // N_OUT*64 bf16 accumulator
    const size_t acc_elems = (size_t)N_OUT_PTS * C_CH;
    float* stats = (float*)((char*)d_ws + acc_elems * sizeof(__hip_bfloat16));

    const size_t clear_bytes = acc_elems * sizeof(__hip_bfloat16) + 2 * C_CH * sizeof(float);
    (void)hipMemsetAsync(d_ws, 0, clear_bytes, stream);

    dim3 g1(M_PTS / (4 * PTS_PER_WAVE), K_OFF);   // (500, 27)
    scatter_gemm<<<g1, 256, 0, stream>>>(x, W, in_idx, out_idx, out_ws);

    bn_stats<<<2048, 256, 0, stream>>>(out_ws, stats);

    bn_apply<<<2048, 256, 0, stream>>>(out_ws, stats, gamma, beta, out);
}